// Round 8
// baseline (310.967 us; speedup 1.0000x reference)
//
#include <hip/hip_runtime.h>
#include <math.h>

#define BB   8
#define HH   384
#define WW   384
#define NN   96
#define HWSZ (HH * WW)
#define NSEG (NN - 1)
#define SEGF 12
#define DMAXV 15.0f
#define CROWS 12                     // rows per block (conv AND render)
#define CBANDS (HH / CROWS)          // 32 -> 256 blocks total
#define FLAGSTRIDE 16                // one flag per 64-B line

// ---------------------------------------------------------------------------
// Separable 7x7: fy = outer(dg,g), fx = outer(g,dg). Recover 1-D taps exactly:
// g[j] = sum_i |fy[i][j]| (sum|dg|=1), dg[i] = sum_j fy[i][j] (sum g = 1).
// ---------------------------------------------------------------------------
__device__ inline void load_taps(const float* __restrict__ fltr,
                                 float* __restrict__ sg, float* __restrict__ sdg)
{
    int tid = threadIdx.x;
    if (tid < 7) {
        float s = 0.f;
#pragma unroll
        for (int i = 0; i < 7; ++i) s += fabsf(fltr[i * 7 + tid]);
        sg[tid] = s;
    } else if (tid < 14) {
        int r = tid - 7;
        float s = 0.f;
#pragma unroll
        for (int j = 0; j < 7; ++j) s += fltr[r * 7 + j];
        sdg[r] = s;
    }
    __syncthreads();
}

// device-scope flag load/store — pure loads while spinning (no RMW ping-pong)
__device__ inline unsigned int flag_ld(const unsigned int* p) {
    return __hip_atomic_load(p, __ATOMIC_ACQUIRE, __HIP_MEMORY_SCOPE_AGENT);
}
__device__ inline void flag_st(unsigned int* p, unsigned int v) {
    __hip_atomic_store(p, v, __ATOMIC_RELEASE, __HIP_MEMORY_SCOPE_AGENT);
}

// Bilinear sample, channel-interleaved 2-ch image; ref-identical math.
// Paired 16-B row loads (corners x0,x0+1 contiguous); edge clamp via select.
__device__ inline float2 bilin2i(const float2* __restrict__ img, float py, float px)
{
    float y = fminf(fmaxf(py, 0.0f), (float)(HH - 1));
    float x = fminf(fmaxf(px, 0.0f), (float)(WW - 1));
    int y0 = (int)floorf(y);
    int x0 = (int)floorf(x);
    int y1 = min(y0 + 1, HH - 1);
    bool xedge = (x0 + 1 > WW - 1);
    float wy = y - (float)y0;
    float wx = x - (float)x0;
    float4 r0 = *(const float4*)(img + y0 * WW + x0);
    float4 r1 = *(const float4*)(img + y1 * WW + x0);
    float2 v00 = make_float2(r0.x, r0.y);
    float2 v01 = xedge ? v00 : make_float2(r0.z, r0.w);
    float2 v10 = make_float2(r1.x, r1.y);
    float2 v11 = xedge ? v10 : make_float2(r1.z, r1.w);
    float w00 = (1.f - wy) * (1.f - wx);
    float w01 = (1.f - wy) * wx;
    float w10 = wy * (1.f - wx);
    float w11 = wy * wx;
    return make_float2(v00.x * w00 + v01.x * w01 + v10.x * w10 + v11.x * w11,
                       v00.y * w00 + v01.y * w01 + v10.y * w10 + v11.y * w11);
}

__device__ inline void write_seg(float* __restrict__ r,
                                 float py, float px, float qy, float qx, float wseg)
{
    float aby = qy - py, abx = qx - px;
    float denom = aby * aby + abx * abx + 1e-8f;
    float aab = py * aby + px * abx;
    float aa  = py * py + px * px;
    float reach = DMAXV + wseg;
    r[0]  = py;   r[1]  = px;
    r[2]  = aby;  r[3]  = abx;
    r[4]  = aab;  r[5]  = denom;
    r[6]  = 1.0f / denom;
    r[7]  = aa;   r[8]  = wseg;
    r[9]  = fminf(py, qy) - reach;
    r[10] = fmaxf(py, qy) + reach;
    r[11] = 0.f;
}

// ---------------------------------------------------------------------------
// Kernel 0: zero the padded cross-block flags (separate dispatch -> visible
// to all fused blocks with no init-ordering race).
// Layout (words): conv_done[b]=b*16, seg_done[b]=128+b*16, rcount=256.
// ---------------------------------------------------------------------------
__global__ __launch_bounds__(512) void init_kernel(unsigned int* __restrict__ flags)
{
    flags[threadIdx.x] = 0u;   // 512 words >= 257 used
}

// ---------------------------------------------------------------------------
// Kernel 1: FUSED conv -> snake -> render. 256 co-resident blocks (6 waves,
// ~52 VGPR -> capacity far above 256 -> spins can't deadlock). Handoff via
// padded per-image flags: producers do fence+release-store / fence+atomicAdd,
// consumers spin on ACQUIRE LOADS only (no RMW ownership ping-pong).
// Image affinity: block blk works on image b = blk&7 in all phases.
// ---------------------------------------------------------------------------
__global__ __launch_bounds__(384) void fused_kernel(
    const float* __restrict__ pred, const float* __restrict__ fltr,
    const float* __restrict__ nodes, const float* __restrict__ widths,
    float2* __restrict__ g2, float2* __restrict__ gw2,
    float* __restrict__ segs, float* __restrict__ partials,
    unsigned int* __restrict__ flags, float* __restrict__ out)
{
    __shared__ float sg[7], sdg[7];
    __shared__ float ss[NSEG * SEGF];
    __shared__ int slo, shi;
    __shared__ float swsum[6];
    __shared__ int is_last;

    unsigned int* conv_done = flags;                      // [b*16]
    unsigned int* seg_done  = flags + 8 * FLAGSTRIDE;     // [b*16]
    unsigned int* rcount    = flags + 16 * FLAGSTRIDE;    // [0]

    load_taps(fltr, sg, sdg);

    int blk = blockIdx.x;            // 256 blocks
    int b = blk & 7;
    int band = blk >> 3;             // 0..31
    int y0 = band * CROWS;
    int tid = threadIdx.x;

    // ================= PHASE 1: conv chunk (all 384 threads) =================
    {
        int x = tid;
        const float* pb = pred + (size_t)b * HWSZ;
        bool xin = (x >= 3) && (x < WW - 3);
        float hg[7], hd[7], hga[7], hda[7];

#pragma unroll
        for (int q = 0; q < CROWS + 6; ++q) {
            float vg = 0.f, vd = 0.f, vga = 0.f, vda = 0.f;
            int r = y0 + q - 3;
            if (r >= 0 && r < HH) {
                const float* row = pb + r * WW;
                if (xin) {
#pragma unroll
                    for (int k = 0; k < 7; ++k) {
                        float v  = row[x + k - 3];
                        float av = fabsf(v);
                        vg  = fmaf(v,  sg[k],  vg);
                        vd  = fmaf(v,  sdg[k], vd);
                        vga = fmaf(av, sg[k],  vga);
                        vda = fmaf(av, sdg[k], vda);
                    }
                } else {
#pragma unroll
                    for (int k = 0; k < 7; ++k) {
                        int ix = x + k - 3;
                        float v  = (ix >= 0 && ix < WW) ? row[ix] : 0.f;
                        float av = fabsf(v);
                        vg  = fmaf(v,  sg[k],  vg);
                        vd  = fmaf(v,  sdg[k], vd);
                        vga = fmaf(av, sg[k],  vga);
                        vda = fmaf(av, sdg[k], vda);
                    }
                }
            }
            hg[q % 7] = vg; hd[q % 7] = vd; hga[q % 7] = vga; hda[q % 7] = vda;

            if (q >= 6) {
                int y = y0 + q - 6;
                float o0 = 0.f, o1 = 0.f, o2 = 0.f, o3 = 0.f;
#pragma unroll
                for (int j = 0; j < 7; ++j) {
                    int s = (q - 6 + j) % 7;
                    o0 = fmaf(hg[s],  sdg[j], o0);
                    o1 = fmaf(hd[s],  sg[j],  o1);
                    o2 = fmaf(hga[s], sdg[j], o2);
                    o3 = fmaf(hda[s], sg[j],  o3);
                }
                size_t gi = (size_t)b * HWSZ + (size_t)y * WW + x;
                g2[gi]  = make_float2(o0 * 10.f, o1 * 10.f);
                gw2[gi] = make_float2(o2 * 10.f, o3 * 10.f);
            }
        }
    }
    __threadfence();                 // release g2/gw2
    __syncthreads();
    if (tid == 0) atomicAdd(&conv_done[b * FLAGSTRIDE], 1u);  // one RMW per block

    // ================= PHASE 2: snake (blocks 0..7, wave 0) =================
    if (blk < 8) {
        if (tid == 0) {
            while (flag_ld(&conv_done[b * FLAGSTRIDE]) < (unsigned)CBANDS)
                __builtin_amdgcn_s_sleep(4);
        }
        __syncthreads();
        __threadfence();             // acquire g2/gw2

        if (tid < 64) {
            int t = tid;
            const float2* gb  = g2  + (size_t)b * HWSZ;
            const float2* gwb = gw2 + (size_t)b * HWSZ;
            const int HALF = NN / 2;
            bool act = (t < HALF);
            bool t0 = (t == 0), tl = (t == HALF - 1);

            float ay = 0.f, ax = 0.f, by = 0.f, bx = 0.f;
            if (act) {
                float4 n4 = *(const float4*)(nodes + (size_t)(b * NN + 2 * t) * 2);
                ay = n4.x; ax = n4.y; by = n4.z; bx = n4.w;
            }

            for (int s = 0; s < 50; ++s) {
                float2 fa = bilin2i(gb, ay, ax);
                float2 fb = bilin2i(gb, by, bx);

                float aLy = __shfl_up(ay, 1, 64),  aLx = __shfl_up(ax, 1, 64);
                float bLy = __shfl_up(by, 1, 64),  bLx = __shfl_up(bx, 1, 64);
                float aRy = __shfl_down(ay, 1, 64), aRx = __shfl_down(ax, 1, 64);
                float bRy = __shfl_down(by, 1, 64), bRx = __shfl_down(bx, 1, 64);
                bLy = t0 ? ay : bLy;  bLx = t0 ? ax : bLx;
                aRy = tl ? by : aRy;  aRx = tl ? bx : aRx;

                float d2m_y = aLy - 2.f * bLy + ay;
                float d2a_y = bLy - 2.f * ay + by;
                float d2b_y = ay  - 2.f * by + aRy;
                float d2p_y = by  - 2.f * aRy + bRy;
                d2m_y = t0 ? d2a_y : d2m_y;
                d2p_y = tl ? d2b_y : d2p_y;
                float d4a_y = d2m_y - 2.f * d2a_y + d2b_y;
                float d4b_y = d2a_y - 2.f * d2b_y + d2p_y;

                float d2m_x = aLx - 2.f * bLx + ax;
                float d2a_x = bLx - 2.f * ax + bx;
                float d2b_x = ax  - 2.f * bx + aRx;
                float d2p_x = bx  - 2.f * aRx + bRx;
                d2m_x = t0 ? d2a_x : d2m_x;
                d2p_x = tl ? d2b_x : d2p_x;
                float d4a_x = d2m_x - 2.f * d2a_x + d2b_x;
                float d4b_x = d2a_x - 2.f * d2b_x + d2p_x;

                ay += 0.1f * (0.01f * d2a_y - 0.01f * d4a_y + fa.x);
                ax += 0.1f * (0.01f * d2a_x - 0.01f * d4a_x + fa.y);
                by += 0.1f * (0.01f * d2b_y - 0.01f * d4b_y + fb.x);
                bx += 0.1f * (0.01f * d2b_x - 0.01f * d4b_x + fb.y);
            }

            float bLy = __shfl_up(by, 1, 64), bLx = __shfl_up(bx, 1, 64);
            float aRy = __shfl_down(ay, 1, 64), aRx = __shfl_down(ax, 1, 64);
            float tay = 0.5f * (by - bLy), tax = 0.5f * (bx - bLx);
            if (t0) { tay = by - ay; tax = bx - ax; }
            float tby = 0.5f * (aRy - ay), tbx = 0.5f * (aRx - ax);
            if (tl) { tby = by - ay; tbx = bx - ax; }

            float na0 = -tax, na1 = tay;
            float nrm = sqrtf(na0 * na0 + na1 * na1) + 1e-6f;
            float nay = na0 / nrm, nax = na1 / nrm;
            float nb0 = -tbx, nb1 = tby;
            nrm = sqrtf(nb0 * nb0 + nb1 * nb1) + 1e-6f;
            float nby = nb0 / nrm, nbx = nb1 / nrm;

            float wa = 0.f, wb = 0.f;
            if (act) { wa = widths[b * NN + 2 * t]; wb = widths[b * NN + 2 * t + 1]; }
            for (int s = 0; s < 10; ++s) {
                float2 pa = bilin2i(gwb, ay + wa * nay, ax + wa * nax);
                float2 ma = bilin2i(gwb, ay - wa * nay, ax - wa * nax);
                float2 pb2 = bilin2i(gwb, by + wb * nby, bx + wb * nbx);
                float2 mb = bilin2i(gwb, by - wb * nby, bx - wb * nbx);
                float fa = 0.5f * ((pa.x * nay + pa.y * nax) - (ma.x * nay + ma.y * nax));
                float fb = 0.5f * ((pb2.x * nby + pb2.y * nbx) - (mb.x * nby + mb.y * nbx));
                wa = fmaxf(wa + 0.1f * fa, 0.5f);
                wb = fmaxf(wb + 0.1f * fb, 0.5f);
            }

            float aRy2 = __shfl_down(ay, 1, 64), aRx2 = __shfl_down(ax, 1, 64);
            float waR  = __shfl_down(wa, 1, 64);
            if (act) {
                float* r0 = segs + (size_t)(b * NSEG + 2 * t) * SEGF;
                write_seg(r0, ay, ax, by, bx, 0.5f * (wa + wb));
                if (t < HALF - 1) {
                    float* r1 = segs + (size_t)(b * NSEG + 2 * t + 1) * SEGF;
                    write_seg(r1, by, bx, aRy2, aRx2, 0.5f * (wb + waR));
                }
            }
        }
        __syncthreads();
        if (tid == 0) {
            __threadfence();         // release segs
            flag_st(&seg_done[b * FLAGSTRIDE], 1u);
        }
    }

    // ================= PHASE 3: render chunk (all blocks) =================
    if (tid == 0) {
        while (flag_ld(&seg_done[b * FLAGSTRIDE]) == 0u)
            __builtin_amdgcn_s_sleep(8);
    }
    __syncthreads();
    __threadfence();                 // acquire segs

    {
        const float* sb = segs + (size_t)b * NSEG * SEGF;
        for (int j = tid; j < NSEG * SEGF; j += 384) ss[j] = sb[j];
        if (tid == 0) { slo = NSEG; shi = -1; }
        __syncthreads();

        float cy0 = (float)y0, cy1 = (float)(y0 + CROWS - 1);
        if (tid < NSEG) {
            float ylo = ss[tid * SEGF + 9];
            float yhi = ss[tid * SEGF + 10];
            if (yhi >= cy0 && ylo <= cy1) {
                atomicMin(&slo, tid);
                atomicMax(&shi, tid);
            }
        }
        __syncthreads();
        int lo = slo, hi = shi;

        float px = (float)tid;
        float px2 = px * px;
        float minv[CROWS];
#pragma unroll
        for (int r = 0; r < CROWS; ++r) minv[r] = DMAXV;

        for (int si = lo; si <= hi; ++si) {
            const float* r = ss + si * SEGF;
            float ay = r[0], ax = r[1], aby = r[2], abx = r[3];
            float aab = r[4], denom = r[5], invd = r[6], aa = r[7], ws = r[8];
            float dotpa_b = fmaf(px, abx, -aab);
            float pa2_b   = fmaf(px, -2.0f * ax, px2 + aa);
#pragma unroll
            for (int ry = 0; ry < CROWS; ++ry) {
                float py = (float)(y0 + ry);
                float dotpa = fmaf(py, aby, dotpa_b);
                float tt = fminf(fmaxf(dotpa * invd, 0.0f), 1.0f);
                float pa2 = fmaf(py, fmaf(py, 1.0f, -2.0f * ay), pa2_b);
                float d2 = fmaf(tt, fmaf(tt, denom, -2.0f * dotpa), pa2);
                float d = sqrtf(fmaxf(d2, 0.0f));
                float v = fmaxf(d - ws, 0.0f);
                minv[ry] = fminf(minv[ry], v);
            }
        }

        const float* pb = pred + (size_t)b * HWSZ + (size_t)y0 * WW + tid;
        float sq = 0.f;
#pragma unroll
        for (int ry = 0; ry < CROWS; ++ry) {
            float diff = pb[ry * WW] - minv[ry];
            sq = fmaf(diff, diff, sq);
        }

#pragma unroll
        for (int off = 32; off > 0; off >>= 1) sq += __shfl_down(sq, off, 64);
        if ((tid & 63) == 0) swsum[tid >> 6] = sq;
        __syncthreads();
        if (tid == 0) {
            float tot = swsum[0] + swsum[1] + swsum[2] + swsum[3] + swsum[4] + swsum[5];
            partials[blk] = tot;
            __threadfence();         // release partial
            unsigned int done = atomicAdd(rcount, 1u);   // one RMW per block
            is_last = (done == (unsigned int)(BB * CBANDS - 1)) ? 1 : 0;
        }
        __syncthreads();

        // last block: parallel final reduction (256 loads spread over threads)
        if (is_last) {
            __threadfence();         // acquire all partials
            float s = (tid < BB * CBANDS) ? partials[tid] : 0.f;
#pragma unroll
            for (int off = 32; off > 0; off >>= 1) s += __shfl_down(s, off, 64);
            if ((tid & 63) == 0) swsum[tid >> 6] = s;
            __syncthreads();
            if (tid == 0) {
                float tot = swsum[0] + swsum[1] + swsum[2] + swsum[3] + swsum[4] + swsum[5];
                out[0] = tot * (1.0f / (float)(BB * HWSZ));
            }
        }
    }
}

extern "C" void kernel_launch(void* const* d_in, const int* in_sizes, int n_in,
                              void* d_out, int out_size, void* d_ws, size_t ws_size,
                              hipStream_t stream)
{
    const float* pred   = (const float*)d_in[0];   // (8,1,384,384)
    const float* nodes  = (const float*)d_in[1];   // (8,96,2)
    const float* widths = (const float*)d_in[2];   // (8,96)
    const float* fltr   = (const float*)d_in[3];   // (2,1,7,7)
    float* out = (float*)d_out;

    float* ws    = (float*)d_ws;
    float* g2    = ws;                               // B*HW*2 interleaved
    float* gw2   = g2 + (size_t)2 * BB * HWSZ;       // B*HW*2
    float* segs  = gw2 + (size_t)2 * BB * HWSZ;      // B*95*12
    float* partials = segs + (size_t)BB * NSEG * SEGF;  // 256
    unsigned int* flags = (unsigned int*)(partials + BB * CBANDS); // 512 words padded

    init_kernel<<<1, 512, 0, stream>>>(flags);
    fused_kernel<<<BB * CBANDS, 384, 0, stream>>>(
        pred, fltr, nodes, widths, (float2*)g2, (float2*)gw2,
        segs, partials, flags, out);
}

// Round 9
// 139.381 us; speedup vs baseline: 2.2311x; 2.2311x over previous
//
#include <hip/hip_runtime.h>
#include <math.h>

#define BB   8
#define HH   384
#define WW   384
#define NN   96
#define HWSZ (HH * WW)
#define NSEG (NN - 1)
#define SEGF 12
#define DMAXV 15.0f
#define ROWS_PER_BLK 12
#define NCHUNK (HH / ROWS_PER_BLK)   // 32
#define CROWS 12
#define CBANDS (HH / CROWS)          // 32

// ---------------------------------------------------------------------------
// Separable 7x7: fy = outer(dg,g), fx = outer(g,dg). Recover 1-D taps exactly:
// g[j] = sum_i |fy[i][j]| (sum|dg|=1), dg[i] = sum_j fy[i][j] (sum g = 1).
// ---------------------------------------------------------------------------
__device__ inline void load_taps(const float* __restrict__ fltr,
                                 float* __restrict__ sg, float* __restrict__ sdg)
{
    int tid = threadIdx.x;
    if (tid < 7) {
        float s = 0.f;
#pragma unroll
        for (int i = 0; i < 7; ++i) s += fabsf(fltr[i * 7 + tid]);
        sg[tid] = s;
    } else if (tid < 14) {
        int r = tid - 7;
        float s = 0.f;
#pragma unroll
        for (int j = 0; j < 7; ++j) s += fltr[r * 7 + j];
        sdg[r] = s;
    }
    __syncthreads();
}

// ---------------------------------------------------------------------------
// Kernel 1 (= R6): fused separable conv, XCD-co-located (b = blk&7), vertical
// pass through a 7-row register ring. Also inits render reduction slots.
// ---------------------------------------------------------------------------
__global__ __launch_bounds__(384) void conv_fused(
    const float* __restrict__ pred, const float* __restrict__ fltr,
    float2* __restrict__ g2, float2* __restrict__ gw2,
    float* __restrict__ accum, unsigned int* __restrict__ counter)
{
    __shared__ float sg[7], sdg[7];
    load_taps(fltr, sg, sdg);
    if (blockIdx.x == 0 && threadIdx.x == 0) {
        atomicExch(accum, 0.0f);
        atomicExch(counter, 0u);
    }

    int blk = blockIdx.x;            // 256 blocks
    int b = blk & 7;
    int band = blk >> 3;
    int y0 = band * CROWS;
    int x = threadIdx.x;
    const float* pb = pred + (size_t)b * HWSZ;
    bool xin = (x >= 3) && (x < WW - 3);

    float hg[7], hd[7], hga[7], hda[7];

#pragma unroll
    for (int q = 0; q < CROWS + 6; ++q) {
        float vg = 0.f, vd = 0.f, vga = 0.f, vda = 0.f;
        int r = y0 + q - 3;
        if (r >= 0 && r < HH) {
            const float* row = pb + r * WW;
            if (xin) {
#pragma unroll
                for (int k = 0; k < 7; ++k) {
                    float v  = row[x + k - 3];
                    float av = fabsf(v);
                    vg  = fmaf(v,  sg[k],  vg);
                    vd  = fmaf(v,  sdg[k], vd);
                    vga = fmaf(av, sg[k],  vga);
                    vda = fmaf(av, sdg[k], vda);
                }
            } else {
#pragma unroll
                for (int k = 0; k < 7; ++k) {
                    int ix = x + k - 3;
                    float v  = (ix >= 0 && ix < WW) ? row[ix] : 0.f;
                    float av = fabsf(v);
                    vg  = fmaf(v,  sg[k],  vg);
                    vd  = fmaf(v,  sdg[k], vd);
                    vga = fmaf(av, sg[k],  vga);
                    vda = fmaf(av, sdg[k], vda);
                }
            }
        }
        hg[q % 7] = vg; hd[q % 7] = vd; hga[q % 7] = vga; hda[q % 7] = vda;

        if (q >= 6) {
            int y = y0 + q - 6;
            float o0 = 0.f, o1 = 0.f, o2 = 0.f, o3 = 0.f;
#pragma unroll
            for (int j = 0; j < 7; ++j) {
                int s = (q - 6 + j) % 7;
                o0 = fmaf(hg[s],  sdg[j], o0);
                o1 = fmaf(hd[s],  sg[j],  o1);
                o2 = fmaf(hga[s], sdg[j], o2);
                o3 = fmaf(hda[s], sg[j],  o3);
            }
            size_t gi = (size_t)b * HWSZ + (size_t)y * WW + x;
            g2[gi]  = make_float2(o0 * 10.f, o1 * 10.f);
            gw2[gi] = make_float2(o2 * 10.f, o3 * 10.f);
        }
    }
}

// ---------------------------------------------------------------------------
// Cached bilinear gather. Positions move <<1 px per snake step, so the 2x2
// corner cell is usually unchanged -> keep the two 16-B row pairs in registers
// and reload ONLY when this lane's integer cell changes (exec-masked load:
// unchanged lanes contribute ZERO L1 transactions — the divergent-gather TA
// serialization was the snake bottleneck). Values are bitwise identical.
// ---------------------------------------------------------------------------
struct GCache { int iy, ix; float4 r0, r1; };
__device__ inline void gc_init(GCache& c) { c.iy = -1 << 30; c.ix = -1 << 30; }

__device__ inline float2 bilin2c(const float2* __restrict__ img, float py, float px,
                                 GCache& c)
{
    float y = fminf(fmaxf(py, 0.0f), (float)(HH - 1));
    float x = fminf(fmaxf(px, 0.0f), (float)(WW - 1));
    int y0 = (int)floorf(y);
    int x0 = (int)floorf(x);
    if (y0 != c.iy || x0 != c.ix) {
        int y1 = min(y0 + 1, HH - 1);
        c.r0 = *(const float4*)(img + y0 * WW + x0);   // v00 | v01
        c.r1 = *(const float4*)(img + y1 * WW + x0);   // v10 | v11
        c.iy = y0; c.ix = x0;
    }
    bool xedge = (x0 + 1 > WW - 1);
    float wy = y - (float)y0;
    float wx = x - (float)x0;
    float2 v00 = make_float2(c.r0.x, c.r0.y);
    float2 v01 = xedge ? v00 : make_float2(c.r0.z, c.r0.w);
    float2 v10 = make_float2(c.r1.x, c.r1.y);
    float2 v11 = xedge ? v10 : make_float2(c.r1.z, c.r1.w);
    float w00 = (1.f - wy) * (1.f - wx);
    float w01 = (1.f - wy) * wx;
    float w10 = wy * (1.f - wx);
    float w11 = wy * wx;
    return make_float2(v00.x * w00 + v01.x * w01 + v10.x * w10 + v11.x * w11,
                       v00.y * w00 + v01.y * w01 + v10.y * w10 + v11.y * w11);
}

__device__ inline void write_seg(float* __restrict__ r,
                                 float py, float px, float qy, float qx, float wseg)
{
    float aby = qy - py, abx = qx - px;
    float denom = aby * aby + abx * abx + 1e-8f;
    float aab = py * aby + px * abx;
    float aa  = py * py + px * px;
    float reach = DMAXV + wseg;
    r[0]  = py;   r[1]  = px;
    r[2]  = aby;  r[3]  = abx;
    r[4]  = aab;  r[5]  = denom;
    r[6]  = 1.0f / denom;
    r[7]  = aa;   r[8]  = wseg;
    r[9]  = fminf(py, qy) - reach;
    r[10] = fmaxf(py, qy) + reach;
    r[11] = 0.f;
}

// ---------------------------------------------------------------------------
// Kernel 2: snake — one wave per sample, thread t owns nodes 2t,2t+1; all
// neighbor exchange by shuffle; corner-cached gathers (see bilin2c).
// ---------------------------------------------------------------------------
__global__ __launch_bounds__(64) void snake_kernel(
    const float* __restrict__ nodes, const float* __restrict__ widths,
    const float* __restrict__ g2, const float* __restrict__ gw2,
    float* __restrict__ segs)
{
    int b = blockIdx.x;
    int t = threadIdx.x;

    const float2* gb  = (const float2*)g2  + (size_t)b * HWSZ;
    const float2* gwb = (const float2*)gw2 + (size_t)b * HWSZ;
    const int HALF = NN / 2;       // 48
    bool act = (t < HALF);
    bool t0 = (t == 0), tl = (t == HALF - 1);

    float ay = 0.f, ax = 0.f, by = 0.f, bx = 0.f;
    if (act) {
        float4 n4 = *(const float4*)(nodes + (size_t)(b * NN + 2 * t) * 2);
        ay = n4.x; ax = n4.y; by = n4.z; bx = n4.w;
    }

    GCache ca, cb;
    gc_init(ca); gc_init(cb);

    // ---- 50 position steps ----
    for (int s = 0; s < 50; ++s) {
        float2 fa = bilin2c(gb, ay, ax, ca);
        float2 fb = bilin2c(gb, by, bx, cb);

        float aLy = __shfl_up(ay, 1, 64),  aLx = __shfl_up(ax, 1, 64);
        float bLy = __shfl_up(by, 1, 64),  bLx = __shfl_up(bx, 1, 64);
        float aRy = __shfl_down(ay, 1, 64), aRx = __shfl_down(ax, 1, 64);
        float bRy = __shfl_down(by, 1, 64), bRx = __shfl_down(bx, 1, 64);
        bLy = t0 ? ay : bLy;  bLx = t0 ? ax : bLx;
        aRy = tl ? by : aRy;  aRx = tl ? bx : aRx;

        float d2m_y = aLy - 2.f * bLy + ay;
        float d2a_y = bLy - 2.f * ay + by;
        float d2b_y = ay  - 2.f * by + aRy;
        float d2p_y = by  - 2.f * aRy + bRy;
        d2m_y = t0 ? d2a_y : d2m_y;
        d2p_y = tl ? d2b_y : d2p_y;
        float d4a_y = d2m_y - 2.f * d2a_y + d2b_y;
        float d4b_y = d2a_y - 2.f * d2b_y + d2p_y;

        float d2m_x = aLx - 2.f * bLx + ax;
        float d2a_x = bLx - 2.f * ax + bx;
        float d2b_x = ax  - 2.f * bx + aRx;
        float d2p_x = bx  - 2.f * aRx + bRx;
        d2m_x = t0 ? d2a_x : d2m_x;
        d2p_x = tl ? d2b_x : d2p_x;
        float d4a_x = d2m_x - 2.f * d2a_x + d2b_x;
        float d4b_x = d2a_x - 2.f * d2b_x + d2p_x;

        ay += 0.1f * (0.01f * d2a_y - 0.01f * d4a_y + fa.x);
        ax += 0.1f * (0.01f * d2a_x - 0.01f * d4a_x + fa.y);
        by += 0.1f * (0.01f * d2b_y - 0.01f * d4b_y + fb.x);
        bx += 0.1f * (0.01f * d2b_x - 0.01f * d4b_x + fb.y);
    }

    // ---- tangent / outward normal ----
    {
        float bLy = __shfl_up(by, 1, 64), bLx = __shfl_up(bx, 1, 64);
        float aRy = __shfl_down(ay, 1, 64), aRx = __shfl_down(ax, 1, 64);
        float tay = 0.5f * (by - bLy), tax = 0.5f * (bx - bLx);
        if (t0) { tay = by - ay; tax = bx - ax; }
        float tby = 0.5f * (aRy - ay), tbx = 0.5f * (aRx - ax);
        if (tl) { tby = by - ay; tbx = bx - ax; }

        float na0 = -tax, na1 = tay;
        float nrm = sqrtf(na0 * na0 + na1 * na1) + 1e-6f;
        float nay = na0 / nrm, nax = na1 / nrm;
        float nb0 = -tbx, nb1 = tby;
        nrm = sqrtf(nb0 * nb0 + nb1 * nb1) + 1e-6f;
        float nby = nb0 / nrm, nbx = nb1 / nrm;

        // ---- 10 width steps, 4 cached probe sites ----
        float wa = 0.f, wb = 0.f;
        if (act) { wa = widths[b * NN + 2 * t]; wb = widths[b * NN + 2 * t + 1]; }
        GCache cpa, cma, cpb, cmb;
        gc_init(cpa); gc_init(cma); gc_init(cpb); gc_init(cmb);
        for (int s = 0; s < 10; ++s) {
            float2 pa = bilin2c(gwb, ay + wa * nay, ax + wa * nax, cpa);
            float2 ma = bilin2c(gwb, ay - wa * nay, ax - wa * nax, cma);
            float2 pb2 = bilin2c(gwb, by + wb * nby, bx + wb * nbx, cpb);
            float2 mb = bilin2c(gwb, by - wb * nby, bx - wb * nbx, cmb);
            float fa = 0.5f * ((pa.x * nay + pa.y * nax) - (ma.x * nay + ma.y * nax));
            float fb = 0.5f * ((pb2.x * nby + pb2.y * nbx) - (mb.x * nby + mb.y * nbx));
            wa = fmaxf(wa + 0.1f * fa, 0.5f);
            wb = fmaxf(wb + 0.1f * fb, 0.5f);
        }

        // ---- segment records ----
        float aRy2 = __shfl_down(ay, 1, 64), aRx2 = __shfl_down(ax, 1, 64);
        float waR  = __shfl_down(wa, 1, 64);
        if (act) {
            float* r0 = segs + (size_t)(b * NSEG + 2 * t) * SEGF;
            write_seg(r0, ay, ax, by, bx, 0.5f * (wa + wb));
            if (t < HALF - 1) {
                float* r1 = segs + (size_t)(b * NSEG + 2 * t + 1) * SEGF;
                write_seg(r1, by, bx, aRy2, aRx2, 0.5f * (wb + waR));
            }
        }
    }
}

// ---------------------------------------------------------------------------
// Kernel 3 (= R6): render 12 rows/block, uniform per-chunk segment window,
// outer-seg/inner-row registers, fused last-block reduction (256 staggered
// blocks x 2 atomics — no storm).
// ---------------------------------------------------------------------------
__global__ __launch_bounds__(384) void render_kernel(
    const float* __restrict__ pred, const float* __restrict__ segs,
    float* __restrict__ accum, unsigned int* __restrict__ counter,
    float* __restrict__ out)
{
    __shared__ float ss[NSEG * SEGF];
    __shared__ int slo, shi;
    __shared__ float swsum[6];

    int blk = blockIdx.x;
    int b = blk & 7;
    int chunk = blk >> 3;
    int y0 = chunk * ROWS_PER_BLK;
    int t = threadIdx.x;

    const float* sb = segs + (size_t)b * NSEG * SEGF;
    for (int j = t; j < NSEG * SEGF; j += 384) ss[j] = sb[j];
    if (t == 0) { slo = NSEG; shi = -1; }
    __syncthreads();

    float cy0 = (float)y0, cy1 = (float)(y0 + ROWS_PER_BLK - 1);
    if (t < NSEG) {
        float ylo = ss[t * SEGF + 9];
        float yhi = ss[t * SEGF + 10];
        if (yhi >= cy0 && ylo <= cy1) {
            atomicMin(&slo, t);
            atomicMax(&shi, t);
        }
    }
    __syncthreads();
    int lo = slo, hi = shi;

    float px = (float)t;
    float px2 = px * px;
    float minv[ROWS_PER_BLK];
#pragma unroll
    for (int r = 0; r < ROWS_PER_BLK; ++r) minv[r] = DMAXV;

    for (int si = lo; si <= hi; ++si) {
        const float* r = ss + si * SEGF;
        float ay = r[0], ax = r[1], aby = r[2], abx = r[3];
        float aab = r[4], denom = r[5], invd = r[6], aa = r[7], ws = r[8];
        float dotpa_b = fmaf(px, abx, -aab);
        float pa2_b   = fmaf(px, -2.0f * ax, px2 + aa);
#pragma unroll
        for (int ry = 0; ry < ROWS_PER_BLK; ++ry) {
            float py = (float)(y0 + ry);
            float dotpa = fmaf(py, aby, dotpa_b);
            float tt = fminf(fmaxf(dotpa * invd, 0.0f), 1.0f);
            float pa2 = fmaf(py, fmaf(py, 1.0f, -2.0f * ay), pa2_b);
            float d2 = fmaf(tt, fmaf(tt, denom, -2.0f * dotpa), pa2);
            float d = sqrtf(fmaxf(d2, 0.0f));
            float v = fmaxf(d - ws, 0.0f);
            minv[ry] = fminf(minv[ry], v);
        }
    }

    const float* pb = pred + (size_t)b * HWSZ + (size_t)y0 * WW + t;
    float sq = 0.f;
#pragma unroll
    for (int ry = 0; ry < ROWS_PER_BLK; ++ry) {
        float diff = pb[ry * WW] - minv[ry];
        sq = fmaf(diff, diff, sq);
    }

#pragma unroll
    for (int off = 32; off > 0; off >>= 1) sq += __shfl_down(sq, off, 64);
    if ((t & 63) == 0) swsum[t >> 6] = sq;
    __syncthreads();
    if (t == 0) {
        float tot = swsum[0] + swsum[1] + swsum[2] + swsum[3] + swsum[4] + swsum[5];
        atomicAdd(accum, tot);
        __threadfence();
        unsigned int done = atomicAdd(counter, 1u);
        if (done == (unsigned int)(BB * NCHUNK - 1)) {
            float total = atomicAdd(accum, 0.0f);   // coherent re-read
            out[0] = total * (1.0f / (float)(BB * HWSZ));
        }
    }
}

extern "C" void kernel_launch(void* const* d_in, const int* in_sizes, int n_in,
                              void* d_out, int out_size, void* d_ws, size_t ws_size,
                              hipStream_t stream)
{
    const float* pred   = (const float*)d_in[0];   // (8,1,384,384)
    const float* nodes  = (const float*)d_in[1];   // (8,96,2)
    const float* widths = (const float*)d_in[2];   // (8,96)
    const float* fltr   = (const float*)d_in[3];   // (2,1,7,7)
    float* out = (float*)d_out;

    float* ws   = (float*)d_ws;
    float* g2   = ws;                               // B*HW*2 interleaved
    float* gw2  = g2 + (size_t)2 * BB * HWSZ;       // B*HW*2
    float* segs = gw2 + (size_t)2 * BB * HWSZ;      // B*95*12
    float* accum = segs + (size_t)BB * NSEG * SEGF; // 1
    unsigned int* counter = (unsigned int*)(accum + 1);

    conv_fused<<<BB * CBANDS, 384, 0, stream>>>(pred, fltr, (float2*)g2, (float2*)gw2,
                                                accum, counter);
    snake_kernel<<<BB, 64, 0, stream>>>(nodes, widths, g2, gw2, segs);
    render_kernel<<<BB * NCHUNK, 384, 0, stream>>>(pred, segs, accum, counter, out);
}